// Round 1
// 207.814 us; speedup vs baseline: 1.0248x; 1.0248x over previous
//
#include <hip/hip_runtime.h>

// CalculateSLayer: a = adj.sum(axis=2) (4096x4096), s_in = a^T @ s, s_out = a @ s.
// Round 8: 256x256 tiles (16 partials instead of 32).
//   Rationale: top-5 dispatches are all 77us 512MiB ws-poison fills => every
//   kernel dispatch < 76.6us; kernel total ~60-90us of the 213us dur. The
//   largest removable kernel-side term is the ws partial round-trip
//   (32 partials x 2 tensors = 84 MB). 256^2 tiles halve it to 42 MB and
//   halve reduce's read. sTj LDS staging DELETED: with 256-wide tiles the
//   case-1 B-frags are 5 short8 global loads/chunk/wave from L2-resident sT
//   (640 KB), issued post-barrier and covered by running case-2 first.
// Carried-forward proven patterns (do not touch):
//   - frag layouts A[m=lane&15][k=8q+j], B[k=8q+j][n=lane&15], C: col=l16,
//     row=4q+r (verified m89/m91; r4/r5 NaN trauma says staging coverage is
//     the bug surface -- sTj removal shrinks that surface)
//   - single barrier per chunk + a_row/aTt double-buffer parity proof
//   - no device-scope fences in hot path (r6: +240us)
// d_out = [s_in (4096x70) | s_out (4096x70)] fp32.

#define N    4096
#define D    70
#define DP   80          // d padded to 5 n-tiles of 16 (rows 70..79 of sT are zero)
#define TILE 256         // block tile (i) x (j); grid 16x16 = 256 blocks = 1/CU
#define NT_D 5
#define NPART 16         // N/TILE partials per output element (was 32)
#define ARP  40          // a_row pitch (shorts): 80B rows, 16B-aligned b128 reads
#define ATP  260         // aTt pitch (shorts): 520B rows, 8B-aligned b64 reads,
                         // dword bank-stride 130%32==2 (same class as proven 132)

typedef short short8  __attribute__((ext_vector_type(8)));   // 8 x bf16 bits
typedef short short4v __attribute__((ext_vector_type(4)));
typedef float f32x4   __attribute__((ext_vector_type(4)));

__device__ __forceinline__ unsigned short f2bf(float f) {
    unsigned u = __builtin_bit_cast(unsigned, f);
    u += 0x7FFFu + ((u >> 16) & 1u);
    return (unsigned short)(u >> 16);
}
__device__ __forceinline__ float bf2f(unsigned short h) {
    unsigned u = (unsigned)h << 16;
    return __builtin_bit_cast(float, u);
}
__device__ __forceinline__ short8 ld_b64x2(const unsigned short* p) {
    short4v lo = *(const short4v*)p;        // 8B aligned
    short4v hi = *(const short4v*)(p + 4);
    return __builtin_shufflevector(lo, hi, 0, 1, 2, 3, 4, 5, 6, 7);
}

// ---------------------------------------------------------------------------
// kernel0: sT[d][n] = bf16(s[n][d]) for d<70, zeros for 70<=d<80 (in d_ws).
// r8: LDS round-trip removed (same thread wrote and read the same element —
// vestigial); float2 row loads; 32 blocks x 128 threads for spread.
// ---------------------------------------------------------------------------
__global__ __launch_bounds__(128) void build_sT(const float* __restrict__ s,
                                                unsigned short* __restrict__ sT) {
    const int t  = threadIdx.x;            // 0..127
    const int n  = blockIdx.x * 128 + t;   // node index
    unsigned short col[DP];
    #pragma unroll
    for (int k = 0; k < D / 2; ++k) {      // 35 float2 loads, 8B-aligned (70*n even)
        float2 v2 = *(const float2*)(s + (size_t)n * D + 2 * k);
        col[2 * k]     = f2bf(v2.x);
        col[2 * k + 1] = f2bf(v2.y);
    }
    #pragma unroll
    for (int d = D; d < DP; ++d) col[d] = 0;
    #pragma unroll
    for (int d = 0; d < DP; ++d)
        sT[(size_t)d * N + n] = col[d];    // 128 x 2B = 256B coalesced per row
}

// ---------------------------------------------------------------------------
// kernel1: per 256x256 tile of a, s_out partial (case 1, contract j) and
// s_in finals-over-block-i (case 2, contract i=256), mfma_f32_16x16x32_bf16.
// 8 chunks of 256i x 32j. 512 threads (8 waves), 1 block/CU.
// USE_WS=true : bf16 partial stores to ws.  false: legacy f32 atomics to out.
// ---------------------------------------------------------------------------
template<bool USE_WS>
__global__ __launch_bounds__(512, 2) void fused_slayer(
    const float* __restrict__ adj,
    const unsigned short* __restrict__ sT,
    unsigned short* __restrict__ wsi,   // [16][N][80] bf16 s_in partials
    unsigned short* __restrict__ wso,   // [16][N][80] bf16 s_out partials
    float* __restrict__ out)            // fallback: [2][N][70] f32
{
    __shared__ __align__(16) unsigned short a_row[2][TILE][ARP]; // [buf][i][j_local<32]
    __shared__ __align__(16) unsigned short aTt[2][32][ATP];     // [buf][j_local][i<256]
    // LDS = 2*256*40*2 + 2*32*260*2 = 40960 + 33280 = 74240 B (gfx950: 160KB/CU)

    const int t    = threadIdx.x;
    const int lane = t & 63;
    const int w    = t >> 6;       // wave 0..7
    const int l16  = lane & 15;
    const int q    = lane >> 4;    // quad 0..3
    const int bx   = blockIdx.x;
    const int by   = blockIdx.y;
    const int I0   = by * TILE;
    const int J0   = bx * TILE;

    // ---- case-2 slot assignment + register B-frags direct from global sT ----
    // 10 slots = 2 m-tiles x 5 n-tiles over 8 waves; waves 0,1 take (mt=w, nt=4).
    // K = 256 now -> 8 ks steps; bfi[8] (32 VGPR), bfe[8] waves 0-1 only.
    const int slot_mt = w & 1;
    const int slot_nt = w >> 1;
    const bool extra  = (w < 2);
    short8 bfi[8], bfe[8];
    {
        const int d = 16 * slot_nt + l16;           // < 64
        #pragma unroll
        for (int ks = 0; ks < 8; ++ks)
            bfi[ks] = *(const short8*)(sT + (size_t)d * N + I0 + 32 * ks + 8 * q);
        if (extra) {
            const int d2 = 64 + l16;                // rows 70..79 are zeros
            #pragma unroll
            for (int ks = 0; ks < 8; ++ks)
                bfe[ks] = *(const short8*)(sT + (size_t)d2 * N + I0 + 32 * ks + 8 * q);
        }
    }

    const f32x4 zero = {0.0f, 0.0f, 0.0f, 0.0f};
    f32x4 acc1[2][NT_D];           // case-1: i-tiles {16w, 128+16w} x 5 d-tiles
    #pragma unroll
    for (int h = 0; h < 2; ++h)
        #pragma unroll
        for (int nt = 0; nt < NT_D; ++nt) acc1[h][nt] = zero;

    const int jp = t & 15;   // j-pair within 32-wide chunk
    const int ir = t >> 4;   // 0..31

    // ---- preload chunk 0: 256 rows x 32 j per chunk, 16 a-pairs/thread ----
    float4 v[8];
    #pragma unroll
    for (int it = 0; it < 8; ++it) {
        int i = 32 * it + ir;
        v[it] = *(const float4*)(adj + (size_t)(I0 + i) * (2 * N)
                                     + (size_t)(J0 + 2 * jp) * 2);
    }

    #pragma unroll 2
    for (int jc = 0; jc < 8; ++jc) {
        const int b = jc & 1;

        // (A) convert chunk jc into buffer b.
        // dbuf proof: buffer b's previous readers (iter jc-2) drained their
        // ds_reads before barrier(jc-1); these writes are after that barrier.
        #pragma unroll
        for (int it = 0; it < 8; ++it) {
            int i = 32 * it + ir;
            unsigned short b0 = f2bf(v[it].x + v[it].y);   // a = ch0 + ch1
            unsigned short b1 = f2bf(v[it].z + v[it].w);
            *(unsigned int*)&a_row[b][i][2 * jp] =
                (unsigned int)b0 | ((unsigned int)b1 << 16);
            aTt[b][2 * jp][i]     = b0;   // 4-way-conflict b16 transpose stores
            aTt[b][2 * jp + 1][i] = b1;
        }
        __syncthreads();   // the only barrier per chunk

        // (C) prefetch chunk jc+1 adj (in flight across MFMA + stores + next (A))
        if (jc < 7) {
            #pragma unroll
            for (int it = 0; it < 8; ++it) {
                int i = 32 * it + ir;
                v[it] = *(const float4*)(adj + (size_t)(I0 + i) * (2 * N)
                                             + (size_t)(J0 + 32 * (jc + 1) + 2 * jp) * 2);
            }
        }

        // (B) case-1 B-frags for THIS chunk from global sT (L2-resident).
        // Issued before case-2 so ~200-300cy L2 latency hides under case-2.
        short8 bq[NT_D];
        #pragma unroll
        for (int nt = 0; nt < NT_D; ++nt)
            bq[nt] = *(const short8*)(sT + (size_t)(16 * nt + l16) * N
                                         + J0 + 32 * jc + 8 * q);

        // ---- case 2 first: s_in finals for this chunk's 32 j's (K=256) ----
        {
            f32x4 acc2 = zero;
            #pragma unroll
            for (int ks = 0; ks < 8; ++ks) {
                short8 af2 = ld_b64x2(&aTt[b][16 * slot_mt + l16][32 * ks + 8 * q]);
                acc2 = __builtin_amdgcn_mfma_f32_16x16x32_bf16(af2, bfi[ks], acc2, 0, 0, 0);
            }
            const int d = 16 * slot_nt + l16;
            #pragma unroll
            for (int r = 0; r < 4; ++r) {
                int gj = J0 + 32 * jc + 16 * slot_mt + 4 * q + r;
                if (USE_WS) {
                    wsi[((size_t)by * N + gj) * DP + d] = f2bf(acc2[r]);
                } else if (d < D) {
                    atomicAdd(&out[(size_t)gj * D + d], acc2[r]);
                }
            }
            if (extra) {
                f32x4 acc3 = zero;
                #pragma unroll
                for (int ks = 0; ks < 8; ++ks) {
                    short8 af3 = ld_b64x2(&aTt[b][16 * w + l16][32 * ks + 8 * q]);
                    acc3 = __builtin_amdgcn_mfma_f32_16x16x32_bf16(af3, bfe[ks], acc3, 0, 0, 0);
                }
                const int d2 = 64 + l16;
                #pragma unroll
                for (int r = 0; r < 4; ++r) {
                    int gj = J0 + 32 * jc + 16 * w + 4 * q + r;
                    if (USE_WS) {
                        wsi[((size_t)by * N + gj) * DP + d2] = f2bf(acc3[r]);
                    } else if (d2 < D) {
                        atomicAdd(&out[(size_t)gj * D + d2], acc3[r]);
                    }
                }
            }
        }

        // ---- case 1: s_out += a_tile @ s_j (two 16-row i-tiles per wave) ----
        #pragma unroll
        for (int h = 0; h < 2; ++h) {
            short8 af = *(const short8*)&a_row[b][128 * h + 16 * w + l16][8 * q];
            #pragma unroll
            for (int nt = 0; nt < NT_D; ++nt)
                acc1[h][nt] = __builtin_amdgcn_mfma_f32_16x16x32_bf16(af, bq[nt], acc1[h][nt], 0, 0, 0);
        }
    }

    // ---- case-1 epilogue: s_out partial for this block's i-range ----
    #pragma unroll
    for (int h = 0; h < 2; ++h)
        #pragma unroll
        for (int nt = 0; nt < NT_D; ++nt) {
            const int d = 16 * nt + l16;
            #pragma unroll
            for (int r = 0; r < 4; ++r) {
                int gi = I0 + 128 * h + 16 * w + 4 * q + r;
                if (USE_WS) {
                    wso[((size_t)bx * N + gi) * DP + d] = f2bf(acc1[h][nt][r]);
                } else if (d < D) {
                    atomicAdd(&out[(size_t)N * D + (size_t)gi * D + d], acc1[h][nt][r]);
                }
            }
        }
}

// ---------------------------------------------------------------------------
// kernel2: reduce 16 bf16 partials -> f32 out.
// ws layout: ushort [which][part<16][N][80]. One thread per (which, j, 8-d
// group); 2*4096*10 = 81920 threads; 128-thread blocks -> 640 blocks.
// ---------------------------------------------------------------------------
__global__ __launch_bounds__(128) void reduce_partials(
    const unsigned short* __restrict__ ws, float* __restrict__ out) {
    const int idx   = blockIdx.x * 128 + threadIdx.x;      // 0 .. 81919
    const int which = idx / (N * (DP / 8));
    const int rem   = idx % (N * (DP / 8));
    const int j     = rem / (DP / 8);
    const int g     = rem % (DP / 8);

    const unsigned short* base = ws + (size_t)which * ((size_t)NPART * N * DP)
                                    + (size_t)j * DP + 8 * g;
    float acc[8];
    #pragma unroll
    for (int e = 0; e < 8; ++e) acc[e] = 0.0f;
    #pragma unroll
    for (int p = 0; p < NPART; ++p) {
        short8 v = *(const short8*)(base + (size_t)p * N * DP);
        #pragma unroll
        for (int e = 0; e < 8; ++e)
            acc[e] += bf2f((unsigned short)v[e]);
    }

    float* o = out + (size_t)which * (N * D) + (size_t)j * D;
    #pragma unroll
    for (int e = 0; e < 8; ++e) {
        int d = 8 * g + e;
        if (d < D) o[d] = acc[e];
    }
}

// ---------------------------------------------------------------------------
extern "C" void kernel_launch(void* const* d_in, const int* in_sizes, int n_in,
                              void* d_out, int out_size, void* d_ws, size_t ws_size,
                              hipStream_t stream) {
    const float* adj = (const float*)d_in[0];
    const float* s   = (const float*)d_in[1];
    float* out = (float*)d_out;

    unsigned short* sT = (unsigned short*)d_ws;              // 80*4096*2 = 655,360 B
    const size_t ST_BYTES   = (size_t)DP * N * sizeof(unsigned short);
    unsigned short* ws_part = (unsigned short*)((char*)d_ws + ST_BYTES);
    const size_t PART_ELEMS = (size_t)NPART * N * DP;        // per output tensor
    const size_t NEED = ST_BYTES + 2 * PART_ELEMS * sizeof(unsigned short); // ~21.6 MB

    build_sT<<<dim3(N / 128), dim3(128), 0, stream>>>(s, sT);

    if (ws_size >= NEED) {
        fused_slayer<true><<<dim3(N / TILE, N / TILE), dim3(512), 0, stream>>>(
            adj, sT, ws_part, ws_part + PART_ELEMS, out);
        reduce_partials<<<dim3(2 * N * (DP / 8) / 128), dim3(128), 0, stream>>>(
            ws_part, out);
    } else {
        hipMemsetAsync(d_out, 0, (size_t)2 * N * D * sizeof(float), stream);
        fused_slayer<false><<<dim3(N / TILE, N / TILE), dim3(512), 0, stream>>>(
            adj, sT, nullptr, nullptr, out);
    }
}